// Round 6
// baseline (416.623 us; speedup 1.0000x reference)
//
#include <hip/hip_runtime.h>
#include <hip/hip_bf16.h>

#define T_DIM 2048
#define B_DIM 32
#define CIN   80
#define H_DIM 256
#define TT    16               // t-tile per conv block
#define NTB   (T_DIM / TT)     // 128
#define NBLK  (B_DIM * NTB)    // 4096 conv blocks

// LIF chunking (warm-up resync; residual <= 2^-48 -> flip prob ~1e-7)
#define CHUNKS 16
#define CLEN  (T_DIM / CHUNKS) // 128
#define WARM  48
#define SEG   16               // timesteps per LDS staging segment

#define NPART 64               // stats partials
#define JPER  (NBLK / NPART)   // 64

typedef unsigned short u16;

// ---- workspace byte offsets ----
#define PS_OFF  ((size_t)64)
#define PQ_OFF  (PS_OFF + (size_t)NBLK * H_DIM * 8)
#define PAR_OFF (PQ_OFF + (size_t)NBLK * H_DIM * 8)
#define WT_OFF  (PAR_OFF + (size_t)768 * 8)
#define PA_OFF  WT_OFF                                  // alias WT (dead after conv)
#define PB_OFF  (WT_OFF + (size_t)NPART * H_DIM * 8)
#define Y_OFF   (WT_OFF + (size_t)H_DIM * CIN * 3 * 8)
#define Y_ELEMS ((size_t)T_DIM * B_DIM * H_DIM)         // 16,777,216
#define XT_OFF  (Y_OFF + Y_ELEMS * 8)                   // tier-A only
#define XT_ELEMS ((size_t)B_DIM * T_DIM * CIN)          // 5,242,880

__device__ __forceinline__ double bf2d(u16 u) {
    union { unsigned int i; float f; } cv;
    cv.i = ((unsigned int)u) << 16;
    return (double)cv.f;
}

__device__ __forceinline__ double ld_in(const void* p, int i, int isbf) {
    if (isbf) return bf2d(((const u16*)p)[i]);
    return (double)((const float*)p)[i];
}

// ---- kernel 0: detect input dtype (bf16 vs f32) ----
__global__ __launch_bounds__(256) void k_detect(const u16* __restrict__ x,
                                                int* __restrict__ flag) {
    __shared__ int cnt[256];
    const int tid = threadIdx.x;
    int c = 0;
    for (int j = 0; j < 8; j++) {
        u16 u = x[tid * 8 + j];
        int e = (u >> 7) & 0xFF;
        if ((u & 0x7FFF) == 0 || (e >= 97 && e <= 157)) c++;
    }
    cnt[tid] = c;
    __syncthreads();
    for (int off = 128; off > 0; off >>= 1) {
        if (tid < off) cnt[tid] += cnt[tid + off];
        __syncthreads();
    }
    if (tid == 0) flag[0] = (cnt[0] >= 1639) ? 1 : 0;
}

// ---- kernel 1: transpose conv_w (H,Cin,3) -> wt[(ci*3+k)*H + h] f64 ----
__global__ __launch_bounds__(256) void k_wprep(const void* __restrict__ w,
                                               const int* __restrict__ flag,
                                               double* __restrict__ wt) {
    const int isbf = flag[0];
    int idx = blockIdx.x * 256 + threadIdx.x;
    if (idx < H_DIM * CIN * 3) {
        int h = idx / (CIN * 3);
        int r = idx - h * (CIN * 3);
        wt[(size_t)r * H_DIM + h] = ld_in(w, idx, isbf);
    }
}

// ---- kernel 1b (tier A): widen x to f64, same (B,T,Cin) layout, 4 elems/thread ----
__global__ __launch_bounds__(256) void k_xprep(const void* __restrict__ x,
                                               const int* __restrict__ flag,
                                               double* __restrict__ xt) {
    const int isbf = flag[0];
    size_t i = ((size_t)blockIdx.x * 256 + threadIdx.x) * 4;
    if (i < XT_ELEMS) {
#pragma unroll
        for (int k = 0; k < 4; k++) xt[i + k] = ld_in(x, (int)(i + k), isbf);
    }
}

// ---- kernel 2A: conv1d via SCALAR x loads (x block-uniform -> SGPRs, no LDS) ----
template <typename YT>
__global__ __launch_bounds__(256, 4) void k_conv_s(const double* __restrict__ xt,
                                                   const void* __restrict__ bias,
                                                   const int* __restrict__ flag,
                                                   const double* __restrict__ wt,
                                                   YT* __restrict__ y,
                                                   double* __restrict__ ps,
                                                   double* __restrict__ pq) {
    const int tb = blockIdx.x;
    const int b  = blockIdx.y;
    const int h  = threadIdx.x;
    const int t0 = tb * TT;

    double acc[TT];
    const double bv = ld_in(bias, h, flag[0]);
#pragma unroll
    for (int i = 0; i < TT; i++) acc[i] = bv;

    const double* xb = xt + (size_t)b * T_DIM * CIN;  // row-major (t, ci)

    const double* wp = wt + h;
    double w0 = wp[0], w1 = wp[H_DIM], w2 = wp[2 * H_DIM];
    for (int ci = 0; ci < CIN; ci++) {
        // per-thread w prefetch for next ci (VGPR, coalesced, hidden by FMAs)
        double wn0 = 0.0, wn1 = 0.0, wn2 = 0.0;
        if (ci + 1 < CIN) {
            const double* wq = wt + (size_t)(ci + 1) * 3 * H_DIM + h;
            wn0 = wq[0]; wn1 = wq[H_DIM]; wn2 = wq[2 * H_DIM];
        }
        // block-uniform x reads -> scalar loads into SGPRs (zero VALU cost)
        double xr[TT + 2];
#pragma unroll
        for (int tl = 0; tl < TT + 2; tl++) {
            int tg = t0 - 1 + tl;
            xr[tl] = (tg >= 0 && tg < T_DIM) ? xb[(size_t)tg * CIN + ci] : 0.0;
        }
#pragma unroll
        for (int tt = 0; tt < TT; tt++) {
            acc[tt] = fma(w2, xr[tt + 2], fma(w1, xr[tt + 1], fma(w0, xr[tt], acc[tt])));
        }
        w0 = wn0; w1 = wn1; w2 = wn2;
    }

    double s1 = 0.0, s2 = 0.0;
#pragma unroll
    for (int tt = 0; tt < TT; tt++) {
        y[((size_t)(t0 + tt) * B_DIM + b) * H_DIM + h] = (YT)acc[tt];
        s1 += acc[tt];
        s2 = fma(acc[tt], acc[tt], s2);
    }
    const int blk = b * NTB + tb;
    ps[(size_t)blk * H_DIM + h] = s1;
    pq[(size_t)blk * H_DIM + h] = s2;
}

// ---- kernel 2B (fallback tiers): R5's LDS-staged conv ----
template <typename YT>
__global__ __launch_bounds__(256, 4) void k_conv(const void* __restrict__ x,
                                                 const void* __restrict__ bias,
                                                 const int* __restrict__ flag,
                                                 const double* __restrict__ wt,
                                                 YT* __restrict__ y,
                                                 double* __restrict__ ps,
                                                 double* __restrict__ pq) {
    __shared__ __align__(16) double xs[CIN * (TT + 2)];
    const int isbf = flag[0];
    const int tb = blockIdx.x;
    const int b  = blockIdx.y;
    const int h  = threadIdx.x;
    const int t0 = tb * TT;

    for (int idx = threadIdx.x; idx < CIN * (TT + 2); idx += 256) {
        int tl = idx / CIN;
        int ci = idx - tl * CIN;
        int tg = t0 - 1 + tl;
        double v = 0.0;
        if (tg >= 0 && tg < T_DIM) v = ld_in(x, (b * T_DIM + tg) * CIN + ci, isbf);
        xs[ci * (TT + 2) + tl] = v;
    }
    __syncthreads();

    double acc[TT];
    const double bv = ld_in(bias, h, isbf);
#pragma unroll
    for (int i = 0; i < TT; i++) acc[i] = bv;

    const double* wp = wt + h;
    double w0 = wp[0], w1 = wp[H_DIM], w2 = wp[2 * H_DIM];
    for (int ci = 0; ci < CIN; ci++) {
        double wn0 = 0.0, wn1 = 0.0, wn2 = 0.0;
        if (ci + 1 < CIN) {
            const double* wq = wt + (size_t)(ci + 1) * 3 * H_DIM + h;
            wn0 = wq[0]; wn1 = wq[H_DIM]; wn2 = wq[2 * H_DIM];
        }
        const double* xr = xs + ci * (TT + 2);
        double x0 = xr[0], x1 = xr[1];
#pragma unroll
        for (int tt = 0; tt < TT; tt += 2) {
            double2 xp = *(const double2*)(xr + tt + 2);
            acc[tt]     = fma(w2, xp.x, fma(w1, x1,   fma(w0, x0, acc[tt])));
            acc[tt + 1] = fma(w2, xp.y, fma(w1, xp.x, fma(w0, x1, acc[tt + 1])));
            x0 = xp.x; x1 = xp.y;
        }
        w0 = wn0; w1 = wn1; w2 = wn2;
    }

    double s1 = 0.0, s2 = 0.0;
#pragma unroll
    for (int tt = 0; tt < TT; tt++) {
        y[((size_t)(t0 + tt) * B_DIM + b) * H_DIM + h] = (YT)acc[tt];
        s1 += acc[tt];
        s2 = fma(acc[tt], acc[tt], s2);
    }
    const int blk = b * NTB + tb;
    ps[(size_t)blk * H_DIM + h] = s1;
    pq[(size_t)blk * H_DIM + h] = s2;
}

// ---- kernel 3a: partial reduce over j (coalesced) ----
__global__ __launch_bounds__(256) void k_statsA(const double* __restrict__ ps,
                                                const double* __restrict__ pq,
                                                double* __restrict__ pa,
                                                double* __restrict__ pb) {
    const int k = blockIdx.x, h = threadIdx.x;
    double s1 = 0.0, s2 = 0.0;
    const int j0 = k * JPER;
    for (int j = j0; j < j0 + JPER; j++) {
        s1 += ps[(size_t)j * H_DIM + h];
        s2 += pq[(size_t)j * H_DIM + h];
    }
    pa[(size_t)k * H_DIM + h] = s1;
    pb[(size_t)k * H_DIM + h] = s2;
}

// ---- kernel 3b: final reduce + fold BN affine ----
__global__ __launch_bounds__(256) void k_statsB(const double* __restrict__ pa,
                                                const double* __restrict__ pb,
                                                const void* __restrict__ gamma,
                                                const void* __restrict__ beta,
                                                const int* __restrict__ flag,
                                                double* __restrict__ par) {
    const int isbf = flag[0];
    const int h = threadIdx.x;
    double s1 = 0.0, s2 = 0.0;
    for (int k = 0; k < NPART; k++) {
        s1 += pa[(size_t)k * H_DIM + h];
        s2 += pb[(size_t)k * H_DIM + h];
    }
    const double N = (double)T_DIM * (double)B_DIM;
    double mean = s1 / N;
    double var  = s2 / N - mean * mean;
    double r    = 1.0 / sqrt(var + 1e-5);
    par[h]       = mean;
    par[256 + h] = r * ld_in(gamma, h, isbf);
    par[512 + h] = ld_in(beta, h, isbf);
}

// ---- kernel 4: chunked LIF, LDS double-buffered segments (unchanged from R5) ----
template <typename YT>
__global__ __launch_bounds__(256, 4) void k_lif(const YT* __restrict__ y,
                                                const double* __restrict__ par,
                                                const int* __restrict__ flag,
                                                void* __restrict__ out) {
    __shared__ YT buf[2][SEG * H_DIM];
    const int isbf = flag[0];
    const int c = blockIdx.x, b = blockIdx.y, h = threadIdx.x;
    const int t_out = c * CLEN;
    int t_begin = t_out - WARM; if (t_begin < 0) t_begin = 0;
    const int t_end = t_out + CLEN;
    const int nseg = (t_end - t_begin) / SEG;

    const double m  = par[h];
    const double A  = par[256 + h];
    const double be = par[512 + h];

    const size_t ST = (size_t)B_DIM * H_DIM;
    const YT* yb = y + (size_t)b * H_DIM + h;
    u16*   ob16 = (u16*)out + (size_t)b * H_DIM + h;
    float* ob32 = (float*)out + (size_t)b * H_DIM + h;

    {
        YT g[SEG];
#pragma unroll
        for (int k = 0; k < SEG; k++) g[k] = yb[(size_t)(t_begin + k) * ST];
#pragma unroll
        for (int k = 0; k < SEG; k++) buf[0][k * H_DIM + h] = g[k];
    }
    __syncthreads();

    double v = 0.0;
    for (int s = 0; s < nseg; s++) {
        const int cur = s & 1;
        const bool more = (s + 1 < nseg);
        YT g[SEG];
        if (more) {
            const int t1 = t_begin + (s + 1) * SEG;
#pragma unroll
            for (int k = 0; k < SEG; k++) g[k] = yb[(size_t)(t1 + k) * ST];
        }
        double r[SEG];
#pragma unroll
        for (int k = 0; k < SEG; k++) r[k] = (double)buf[cur][k * H_DIM + h];
        const int t0s = t_begin + s * SEG;
#pragma unroll
        for (int k = 0; k < SEG; k++) {
            double val = fma(r[k] - m, A, be);
            v = fma(v, 0.5, val);
            bool sp = (v - 1.0) >= 0.0;
            const int t = t0s + k;
            if (t >= t_out) {
                size_t oi = (size_t)t * ST;
                if (isbf) ob16[oi] = sp ? (u16)0x3F80 : (u16)0;
                else      ob32[oi] = sp ? 1.0f : 0.0f;
            }
            v = sp ? 0.0 : v;
        }
        if (more) {
#pragma unroll
            for (int k = 0; k < SEG; k++) buf[cur ^ 1][k * H_DIM + h] = g[k];
        }
        __syncthreads();
    }
}

// ---- diagnostic: ws too small ----
__global__ void k_code(u16* out, float code) {
    if (threadIdx.x == 0 && blockIdx.x == 0) {
        union { unsigned int i; float f; } cv; cv.f = code;
        out[0] = (u16)(cv.i >> 16);
    }
}

extern "C" void kernel_launch(void* const* d_in, const int* in_sizes, int n_in,
                              void* d_out, int out_size, void* d_ws, size_t ws_size,
                              hipStream_t stream) {
    const void* x     = d_in[0];
    const void* w     = d_in[1];
    const void* cb    = d_in[2];
    const void* gamma = d_in[3];
    const void* beta  = d_in[4];

    char* wsb   = (char*)d_ws;
    int* flag   = (int*)wsb;
    double* PS  = (double*)(wsb + PS_OFF);
    double* PQ  = (double*)(wsb + PQ_OFF);
    double* PAR = (double*)(wsb + PAR_OFF);
    double* WT  = (double*)(wsb + WT_OFF);
    double* PA  = (double*)(wsb + PA_OFF);
    double* PB  = (double*)(wsb + PB_OFF);
    void* Yp    = (void*)(wsb + Y_OFF);
    double* XT  = (double*)(wsb + XT_OFF);

    const size_t needA  = XT_OFF + XT_ELEMS * 8;   // 185,047,104
    const size_t need64 = XT_OFF;                   // 143,104,064
    const size_t need32 = Y_OFF + Y_ELEMS * 4;

    if (ws_size < need32) {
        hipMemsetAsync(d_out, 0, (size_t)out_size * 2, stream);
        k_code<<<1, 64, 0, stream>>>((u16*)d_out, 1000.0f);
        return;
    }

    k_detect<<<1, 256, 0, stream>>>((const u16*)x, flag);
    k_wprep<<<dim3((H_DIM * CIN * 3 + 255) / 256), dim3(256), 0, stream>>>(w, flag, WT);

    if (ws_size >= needA) {
        k_xprep<<<dim3((XT_ELEMS / 4 + 255) / 256), dim3(256), 0, stream>>>(x, flag, XT);
        k_conv_s<double><<<dim3(NTB, B_DIM), dim3(256), 0, stream>>>(
            XT, cb, flag, WT, (double*)Yp, PS, PQ);
        k_statsA<<<dim3(NPART), dim3(256), 0, stream>>>(PS, PQ, PA, PB);
        k_statsB<<<dim3(1), dim3(256), 0, stream>>>(PA, PB, gamma, beta, flag, PAR);
        k_lif<double><<<dim3(CHUNKS, B_DIM), dim3(256), 0, stream>>>(
            (const double*)Yp, PAR, flag, d_out);
    } else if (ws_size >= need64) {
        k_conv<double><<<dim3(NTB, B_DIM), dim3(256), 0, stream>>>(
            x, cb, flag, WT, (double*)Yp, PS, PQ);
        k_statsA<<<dim3(NPART), dim3(256), 0, stream>>>(PS, PQ, PA, PB);
        k_statsB<<<dim3(1), dim3(256), 0, stream>>>(PA, PB, gamma, beta, flag, PAR);
        k_lif<double><<<dim3(CHUNKS, B_DIM), dim3(256), 0, stream>>>(
            (const double*)Yp, PAR, flag, d_out);
    } else {
        k_conv<float><<<dim3(NTB, B_DIM), dim3(256), 0, stream>>>(
            x, cb, flag, WT, (float*)Yp, PS, PQ);
        k_statsA<<<dim3(NPART), dim3(256), 0, stream>>>(PS, PQ, PA, PB);
        k_statsB<<<dim3(1), dim3(256), 0, stream>>>(PA, PB, gamma, beta, flag, PAR);
        k_lif<float><<<dim3(CHUNKS, B_DIM), dim3(256), 0, stream>>>(
            (const float*)Yp, PAR, flag, d_out);
    }
}

// Round 7
// 303.345 us; speedup vs baseline: 1.3734x; 1.3734x over previous
//
#include <hip/hip_runtime.h>
#include <hip/hip_bf16.h>

#define T_DIM 2048
#define B_DIM 32
#define CIN   80
#define H_DIM 256
#define TT    16               // t-tile per conv block
#define NTB   (T_DIM / TT)     // 128
#define NBLK  (B_DIM * NTB)    // 4096 conv blocks
#define KTOT  (CIN * 3)        // 240

// LIF chunking (warm-up resync; verified absmax=0 in R5/R6)
#define CHUNKS 16
#define CLEN  (T_DIM / CHUNKS) // 128
#define WARM  48
#define SEG   16

#define NPART 64
#define JPER  (NBLK / NPART)   // 64

typedef unsigned short u16;
typedef __attribute__((ext_vector_type(4))) double d4;

// ---- workspace byte offsets ----
// flag[0]=isbf, flag[1]=mfma_ok
#define PS_OFF  ((size_t)64)
#define PQ_OFF  (PS_OFF + (size_t)NBLK * H_DIM * 8)
#define PAR_OFF (PQ_OFF + (size_t)NBLK * H_DIM * 8)
#define WT_OFF  (PAR_OFF + (size_t)768 * 8)
#define PA_OFF  WT_OFF                                  // alias WT (dead after conv)
#define PB_OFF  (WT_OFF + (size_t)NPART * H_DIM * 8)
#define Y_OFF   (WT_OFF + (size_t)H_DIM * CIN * 3 * 8)
#define Y_ELEMS ((size_t)T_DIM * B_DIM * H_DIM)         // 16,777,216

__device__ __forceinline__ double bf2d(u16 u) {
    union { unsigned int i; float f; } cv;
    cv.i = ((unsigned int)u) << 16;
    return (double)cv.f;
}

__device__ __forceinline__ double ld_in(const void* p, int i, int isbf) {
    if (isbf) return bf2d(((const u16*)p)[i]);
    return (double)((const float*)p)[i];
}

// ---- kernel 0: detect input dtype (bf16 vs f32) ----
__global__ __launch_bounds__(256) void k_detect(const u16* __restrict__ x,
                                                int* __restrict__ flag) {
    __shared__ int cnt[256];
    const int tid = threadIdx.x;
    int c = 0;
    for (int j = 0; j < 8; j++) {
        u16 u = x[tid * 8 + j];
        int e = (u >> 7) & 0xFF;
        if ((u & 0x7FFF) == 0 || (e >= 97 && e <= 157)) c++;
    }
    cnt[tid] = c;
    __syncthreads();
    for (int off = 128; off > 0; off >>= 1) {
        if (tid < off) cnt[tid] += cnt[tid + off];
        __syncthreads();
    }
    if (tid == 0) flag[0] = (cnt[0] >= 1639) ? 1 : 0;
}

// ---- kernel 0b: verify f64 MFMA fragment mapping (asymmetric integer test) ----
// Assumed: A[m][k] at lane m+16k; B[k][n] at lane 16k+n; D[i][j]: j=lane&15,
// i=4*(lane>>4)+reg. Integer values -> exact; any deviation -> flag[1]=0.
__global__ __launch_bounds__(64) void k_mfmachk(int* __restrict__ flag) {
    const int l = threadIdx.x;
    const int i4 = l >> 4, jn = l & 15;
    // this lane's operand elements under the ASSUMED layout
    double a = (double)(jn * 4 + i4 + 1);          // A[m=jn][k=i4]
    double b = (double)(i4 * 16 + jn + 1);         // B[k=i4][n=jn]
    d4 c;
#pragma unroll
    for (int r = 0; r < 4; r++) c[r] = (double)((4 * i4 + r) * 16 + jn);  // C[i][j]
    d4 d = __builtin_amdgcn_mfma_f64_16x16x4f64(a, b, c, 0, 0, 0);
    bool ok = true;
#pragma unroll
    for (int r = 0; r < 4; r++) {
        int i = 4 * i4 + r;
        double ref = (double)(i * 16 + jn);
        for (int k = 0; k < 4; k++)
            ref += (double)(i * 4 + k + 1) * (double)(k * 16 + jn + 1);
        if (d[r] != ref) ok = false;
    }
    if (__all(ok) ? 1 : 0) { if (l == 0) flag[1] = 1; }
    else                   { if (l == 0) flag[1] = 0; }
}

// ---- kernel 1: transpose conv_w (H,Cin,3) -> wt[(ci*3+k)*H + h] f64 ----
__global__ __launch_bounds__(256) void k_wprep(const void* __restrict__ w,
                                               const int* __restrict__ flag,
                                               double* __restrict__ wt) {
    const int isbf = flag[0];
    int idx = blockIdx.x * 256 + threadIdx.x;
    if (idx < H_DIM * CIN * 3) {
        int h = idx / (CIN * 3);
        int r = idx - h * (CIN * 3);
        wt[(size_t)r * H_DIM + h] = ld_in(w, idx, isbf);
    }
}

// ---- kernel 2: conv1d as f64 GEMM. MFMA path (matrix pipe) with VALU fallback ----
template <typename YT>
__global__ __launch_bounds__(256, 4) void k_conv2(const void* __restrict__ x,
                                                  const void* __restrict__ bias,
                                                  const int* __restrict__ flag,
                                                  const double* __restrict__ wt,
                                                  YT* __restrict__ y,
                                                  double* __restrict__ ps,
                                                  double* __restrict__ pq) {
    __shared__ __align__(16) double xs[CIN * (TT + 2)];  // xs[ci*18 + tl], tl0 = t0-1
    const int isbf = flag[0];
    const int tb = blockIdx.x;
    const int b  = blockIdx.y;
    const int t0 = tb * TT;

    for (int idx = threadIdx.x; idx < CIN * (TT + 2); idx += 256) {
        int tl = idx / CIN;
        int ci = idx - tl * CIN;
        int tg = t0 - 1 + tl;
        double v = 0.0;
        if (tg >= 0 && tg < T_DIM) v = ld_in(x, (b * T_DIM + tg) * CIN + ci, isbf);
        xs[ci * (TT + 2) + tl] = v;
    }
    __syncthreads();

    const int blk = b * NTB + tb;

    if (flag[1]) {
        // ---------- MFMA path: D[t][h] = sum_k A[t][k] * B[k][h] ----------
        const int wave = threadIdx.x >> 6;
        const int lane = threadIdx.x & 63;
        const int kq   = lane >> 4;     // k-quad / t-row-group
        const int jn   = lane & 15;     // h within tile (D col), t within tile (A row)
        const int h0w  = wave * 64;     // this wave covers h0w..h0w+63 in 4 tiles

        d4 acc[4];
#pragma unroll
        for (int ht = 0; ht < 4; ht++) {
            double bv = ld_in(bias, h0w + ht * 16 + jn, isbf);
            acc[ht][0] = bv; acc[ht][1] = bv; acc[ht][2] = bv; acc[ht][3] = bv;
        }

        for (int kk = 0; kk < KTOT / 4; kk++) {
            const int k  = kk * 4 + kq;
            const int ci = k / 3;            // magic-mul, VALU co-scheduled w/ MFMA
            const int dk = k - ci * 3;
            double a = xs[ci * (TT + 2) + jn + dk];   // A[t=jn][k]
            const double* wrow = wt + (size_t)k * H_DIM + h0w + jn;
#pragma unroll
            for (int ht = 0; ht < 4; ht++) {
                double bw = wrow[ht * 16];            // B[k][h]
                acc[ht] = __builtin_amdgcn_mfma_f64_16x16x4f64(a, bw, acc[ht], 0, 0, 0);
            }
        }

#pragma unroll
        for (int ht = 0; ht < 4; ht++) {
            const int h = h0w + ht * 16 + jn;
            double s1 = 0.0, s2 = 0.0;
#pragma unroll
            for (int r = 0; r < 4; r++) {
                const int t = t0 + 4 * kq + r;        // D row i = 4*(lane>>4)+r
                y[((size_t)t * B_DIM + b) * H_DIM + h] = (YT)acc[ht][r];
                s1 += acc[ht][r];
                s2 = fma(acc[ht][r], acc[ht][r], s2);
            }
            // reduce over the 4 t-row-groups (lanes differing in bits 4-5)
            s1 += __shfl_xor(s1, 16); s1 += __shfl_xor(s1, 32);
            s2 += __shfl_xor(s2, 16); s2 += __shfl_xor(s2, 32);
            if (kq == 0) {
                ps[(size_t)blk * H_DIM + h] = s1;
                pq[(size_t)blk * H_DIM + h] = s2;
            }
        }
    } else {
        // ---------- fallback: R5's LDS-staged VALU conv (h = threadIdx.x) ----------
        const int h = threadIdx.x;
        double acc[TT];
        const double bv = ld_in(bias, h, isbf);
#pragma unroll
        for (int i = 0; i < TT; i++) acc[i] = bv;

        const double* wp = wt + h;
        double w0 = wp[0], w1 = wp[H_DIM], w2 = wp[2 * H_DIM];
        for (int ci = 0; ci < CIN; ci++) {
            double wn0 = 0.0, wn1 = 0.0, wn2 = 0.0;
            if (ci + 1 < CIN) {
                const double* wq = wt + (size_t)(ci + 1) * 3 * H_DIM + h;
                wn0 = wq[0]; wn1 = wq[H_DIM]; wn2 = wq[2 * H_DIM];
            }
            const double* xr = xs + ci * (TT + 2);
            double x0 = xr[0], x1 = xr[1];
#pragma unroll
            for (int tt = 0; tt < TT; tt += 2) {
                double2 xp = *(const double2*)(xr + tt + 2);
                acc[tt]     = fma(w2, xp.x, fma(w1, x1,   fma(w0, x0, acc[tt])));
                acc[tt + 1] = fma(w2, xp.y, fma(w1, xp.x, fma(w0, x1, acc[tt + 1])));
                x0 = xp.x; x1 = xp.y;
            }
            w0 = wn0; w1 = wn1; w2 = wn2;
        }

        double s1 = 0.0, s2 = 0.0;
#pragma unroll
        for (int tt = 0; tt < TT; tt++) {
            y[((size_t)(t0 + tt) * B_DIM + b) * H_DIM + h] = (YT)acc[tt];
            s1 += acc[tt];
            s2 = fma(acc[tt], acc[tt], s2);
        }
        ps[(size_t)blk * H_DIM + h] = s1;
        pq[(size_t)blk * H_DIM + h] = s2;
    }
}

// ---- kernel 3a: partial reduce over j (coalesced) ----
__global__ __launch_bounds__(256) void k_statsA(const double* __restrict__ ps,
                                                const double* __restrict__ pq,
                                                double* __restrict__ pa,
                                                double* __restrict__ pb) {
    const int k = blockIdx.x, h = threadIdx.x;
    double s1 = 0.0, s2 = 0.0;
    const int j0 = k * JPER;
    for (int j = j0; j < j0 + JPER; j++) {
        s1 += ps[(size_t)j * H_DIM + h];
        s2 += pq[(size_t)j * H_DIM + h];
    }
    pa[(size_t)k * H_DIM + h] = s1;
    pb[(size_t)k * H_DIM + h] = s2;
}

// ---- kernel 3b: final reduce + fold BN affine ----
__global__ __launch_bounds__(256) void k_statsB(const double* __restrict__ pa,
                                                const double* __restrict__ pb,
                                                const void* __restrict__ gamma,
                                                const void* __restrict__ beta,
                                                const int* __restrict__ flag,
                                                double* __restrict__ par) {
    const int isbf = flag[0];
    const int h = threadIdx.x;
    double s1 = 0.0, s2 = 0.0;
    for (int k = 0; k < NPART; k++) {
        s1 += pa[(size_t)k * H_DIM + h];
        s2 += pb[(size_t)k * H_DIM + h];
    }
    const double N = (double)T_DIM * (double)B_DIM;
    double mean = s1 / N;
    double var  = s2 / N - mean * mean;
    double r    = 1.0 / sqrt(var + 1e-5);
    par[h]       = mean;
    par[256 + h] = r * ld_in(gamma, h, isbf);
    par[512 + h] = ld_in(beta, h, isbf);
}

// ---- kernel 4: chunked LIF, LDS double-buffered segments (unchanged from R5) ----
template <typename YT>
__global__ __launch_bounds__(256, 4) void k_lif(const YT* __restrict__ y,
                                                const double* __restrict__ par,
                                                const int* __restrict__ flag,
                                                void* __restrict__ out) {
    __shared__ YT buf[2][SEG * H_DIM];
    const int isbf = flag[0];
    const int c = blockIdx.x, b = blockIdx.y, h = threadIdx.x;
    const int t_out = c * CLEN;
    int t_begin = t_out - WARM; if (t_begin < 0) t_begin = 0;
    const int t_end = t_out + CLEN;
    const int nseg = (t_end - t_begin) / SEG;

    const double m  = par[h];
    const double A  = par[256 + h];
    const double be = par[512 + h];

    const size_t ST = (size_t)B_DIM * H_DIM;
    const YT* yb = y + (size_t)b * H_DIM + h;
    u16*   ob16 = (u16*)out + (size_t)b * H_DIM + h;
    float* ob32 = (float*)out + (size_t)b * H_DIM + h;

    {
        YT g[SEG];
#pragma unroll
        for (int k = 0; k < SEG; k++) g[k] = yb[(size_t)(t_begin + k) * ST];
#pragma unroll
        for (int k = 0; k < SEG; k++) buf[0][k * H_DIM + h] = g[k];
    }
    __syncthreads();

    double v = 0.0;
    for (int s = 0; s < nseg; s++) {
        const int cur = s & 1;
        const bool more = (s + 1 < nseg);
        YT g[SEG];
        if (more) {
            const int t1 = t_begin + (s + 1) * SEG;
#pragma unroll
            for (int k = 0; k < SEG; k++) g[k] = yb[(size_t)(t1 + k) * ST];
        }
        double r[SEG];
#pragma unroll
        for (int k = 0; k < SEG; k++) r[k] = (double)buf[cur][k * H_DIM + h];
        const int t0s = t_begin + s * SEG;
#pragma unroll
        for (int k = 0; k < SEG; k++) {
            double val = fma(r[k] - m, A, be);
            v = fma(v, 0.5, val);
            bool sp = (v - 1.0) >= 0.0;
            const int t = t0s + k;
            if (t >= t_out) {
                size_t oi = (size_t)t * ST;
                if (isbf) ob16[oi] = sp ? (u16)0x3F80 : (u16)0;
                else      ob32[oi] = sp ? 1.0f : 0.0f;
            }
            v = sp ? 0.0 : v;
        }
        if (more) {
#pragma unroll
            for (int k = 0; k < SEG; k++) buf[cur ^ 1][k * H_DIM + h] = g[k];
        }
        __syncthreads();
    }
}

// ---- diagnostic: ws too small ----
__global__ void k_code(u16* out, float code) {
    if (threadIdx.x == 0 && blockIdx.x == 0) {
        union { unsigned int i; float f; } cv; cv.f = code;
        out[0] = (u16)(cv.i >> 16);
    }
}

extern "C" void kernel_launch(void* const* d_in, const int* in_sizes, int n_in,
                              void* d_out, int out_size, void* d_ws, size_t ws_size,
                              hipStream_t stream) {
    const void* x     = d_in[0];
    const void* w     = d_in[1];
    const void* cb    = d_in[2];
    const void* gamma = d_in[3];
    const void* beta  = d_in[4];

    char* wsb   = (char*)d_ws;
    int* flag   = (int*)wsb;
    double* PS  = (double*)(wsb + PS_OFF);
    double* PQ  = (double*)(wsb + PQ_OFF);
    double* PAR = (double*)(wsb + PAR_OFF);
    double* WT  = (double*)(wsb + WT_OFF);
    double* PA  = (double*)(wsb + PA_OFF);
    double* PB  = (double*)(wsb + PB_OFF);
    void* Yp    = (void*)(wsb + Y_OFF);

    const size_t need64 = Y_OFF + Y_ELEMS * 8;   // 143,104,064
    const size_t need32 = Y_OFF + Y_ELEMS * 4;

    if (ws_size < need32) {
        hipMemsetAsync(d_out, 0, (size_t)out_size * 2, stream);
        k_code<<<1, 64, 0, stream>>>((u16*)d_out, 1000.0f);
        return;
    }

    k_detect<<<1, 256, 0, stream>>>((const u16*)x, flag);
    k_mfmachk<<<1, 64, 0, stream>>>(flag);
    k_wprep<<<dim3((H_DIM * CIN * 3 + 255) / 256), dim3(256), 0, stream>>>(w, flag, WT);

    if (ws_size >= need64) {
        k_conv2<double><<<dim3(NTB, B_DIM), dim3(256), 0, stream>>>(
            x, cb, flag, WT, (double*)Yp, PS, PQ);
        k_statsA<<<dim3(NPART), dim3(256), 0, stream>>>(PS, PQ, PA, PB);
        k_statsB<<<dim3(1), dim3(256), 0, stream>>>(PA, PB, gamma, beta, flag, PAR);
        k_lif<double><<<dim3(CHUNKS, B_DIM), dim3(256), 0, stream>>>(
            (const double*)Yp, PAR, flag, d_out);
    } else {
        k_conv2<float><<<dim3(NTB, B_DIM), dim3(256), 0, stream>>>(
            x, cb, flag, WT, (float*)Yp, PS, PQ);
        k_statsA<<<dim3(NPART), dim3(256), 0, stream>>>(PS, PQ, PA, PB);
        k_statsB<<<dim3(1), dim3(256), 0, stream>>>(PA, PB, gamma, beta, flag, PAR);
        k_lif<float><<<dim3(CHUNKS, B_DIM), dim3(256), 0, stream>>>(
            (const float*)Yp, PAR, flag, d_out);
    }
}